// Round 9
// baseline (119.639 us; speedup 1.0000x reference)
//
#include <hip/hip_runtime.h>
#include <hip/hip_bf16.h>
#include <stdint.h>

typedef __bf16 bf16x8 __attribute__((ext_vector_type(8)));
typedef float  f32x4  __attribute__((ext_vector_type(4)));

#define B_   2
#define T_   2048
#define H_   16
#define DH_  64
#define DM_  1024
#define BH_  (B_*H_)   // 32
#define M_   (B_*T_)   // 4096

#define QSCALE 0.18033688f   // 1/sqrt(64) * log2(e), folded into Q
#define FIXED_M 8.0f         // static softmax max (exp2 domain)

// ---- async global->LDS, 16B per lane; LDS dest must be wave-uniform base ----
static __device__ __forceinline__ void gload_lds16(const void* g, void* lds) {
  __builtin_amdgcn_global_load_lds(
      (const __attribute__((address_space(1))) void*)(uintptr_t)g,
      (__attribute__((address_space(3))) void*)(uint32_t)(uintptr_t)lds,
      16, 0, 0);
}

// ---------------- conversion kernels ----------------
__global__ void k_cvt_bf16(const float* __restrict__ in, __hip_bfloat16* __restrict__ out, int n4) {
  int i = blockIdx.x * blockDim.x + threadIdx.x;
  if (i < n4) {
    float4 v = reinterpret_cast<const float4*>(in)[i];
    alignas(8) __hip_bfloat16 t[4] = {__float2bfloat16(v.x), __float2bfloat16(v.y),
                                      __float2bfloat16(v.z), __float2bfloat16(v.w)};
    reinterpret_cast<uint2*>(out)[i] = *reinterpret_cast<const uint2*>(t);
  }
}

// in [K][N] f32 row-major -> out [N][K] bf16 row-major (B^T for gemm_bt)
__global__ void k_cvtT(const float* __restrict__ in, __hip_bfloat16* __restrict__ out, int K, int N) {
  __shared__ float tile[32][33];
  int n0 = blockIdx.x * 32, k0 = blockIdx.y * 32;
  int tid = threadIdx.x;
  int kl = tid >> 3, n4 = (tid & 7) * 4;
  float4 v = *reinterpret_cast<const float4*>(in + (size_t)(k0 + kl) * N + n0 + n4);
  tile[kl][n4 + 0] = v.x; tile[kl][n4 + 1] = v.y; tile[kl][n4 + 2] = v.z; tile[kl][n4 + 3] = v.w;
  __syncthreads();
  int nl = tid >> 3, k4 = (tid & 7) * 4;
  alignas(8) __hip_bfloat16 t[4];
  #pragma unroll
  for (int j = 0; j < 4; ++j) t[j] = __float2bfloat16(tile[k4 + j][nl]);
  *reinterpret_cast<uint2*>(out + (size_t)(n0 + nl) * K + k0 + k4) = *reinterpret_cast<const uint2*>(t);
}

// ---------- templated bf16 GEMM core (B^T input), BK=32, 4 waves ----------
template<int BM, int BN, int FM, int FN>
static __device__ __forceinline__ void gemm_core(
    const __hip_bfloat16* __restrict__ A, const __hip_bfloat16* __restrict__ BT,
    int K, int brow, int bcol, __hip_bfloat16* As, __hip_bfloat16* Bs, f32x4 acc[FM][FN]) {
  constexpr int WGN = BN / (16 * FN);
  const int tid = threadIdx.x, wave = tid >> 6, lane = tid & 63;
  const int wr = wave / WGN, wc = wave % WGN;
  const int llo = lane & 15, lhi = lane >> 4;
  for (int k0 = 0; k0 < K; k0 += 32) {
    #pragma unroll
    for (int c = wave; c < BM / 16; c += 4)
      gload_lds16(A + (size_t)(brow + c * 16 + (lane >> 2)) * K + k0 + (lane & 3) * 8,
                  As + c * 16 * 32);
    #pragma unroll
    for (int c = wave; c < BN / 16; c += 4)
      gload_lds16(BT + (size_t)(bcol + c * 16 + (lane >> 2)) * K + k0 + (lane & 3) * 8,
                  Bs + c * 16 * 32);
    __syncthreads();
    bf16x8 a[FM], b[FN];
    #pragma unroll
    for (int i = 0; i < FM; ++i)
      a[i] = *reinterpret_cast<const bf16x8*>(As + (wr * FM * 16 + i * 16 + llo) * 32 + lhi * 8);
    #pragma unroll
    for (int j = 0; j < FN; ++j)
      b[j] = *reinterpret_cast<const bf16x8*>(Bs + (wc * FN * 16 + j * 16 + llo) * 32 + lhi * 8);
    #pragma unroll
    for (int i = 0; i < FM; ++i)
      #pragma unroll
      for (int j = 0; j < FN; ++j)
        acc[i][j] = __builtin_amdgcn_mfma_f32_16x16x32_bf16(a[i], b[j], acc[i][j], 0, 0, 0);
    __syncthreads();
  }
}

// GEMM1: qkv = xb @ w_qkv ; Q (pre-scaled) / K as [bh][t][dh]; V directly
// transposed to [bh][dh][t] (4 consecutive t per lane -> packed 8B store).
__global__ __launch_bounds__(256) void k_gemm_qkv(
    const __hip_bfloat16* __restrict__ A, const __hip_bfloat16* __restrict__ BT,
    __hip_bfloat16* __restrict__ q_ws, __hip_bfloat16* __restrict__ k_ws,
    __hip_bfloat16* __restrict__ vT) {
  alignas(16) __shared__ __hip_bfloat16 As[128 * 32];
  alignas(16) __shared__ __hip_bfloat16 Bs[128 * 32];
  f32x4 acc[4][4] = {};
  const int brow = blockIdx.y * 128, bcol = blockIdx.x * 128;
  gemm_core<128, 128, 4, 4>(A, BT, DM_, brow, bcol, As, Bs, acc);
  const int tid = threadIdx.x, wave = tid >> 6, lane = tid & 63;
  const int wr = wave >> 1, wc = wave & 1;
  const int llo = lane & 15, lhi = lane >> 4;
  #pragma unroll
  for (int i = 0; i < 4; ++i) {
    const int tbase = brow + wr * 64 + i * 16 + lhi * 4;  // 4 consecutive t
    const int b = tbase >> 11, t = tbase & 2047;
    #pragma unroll
    for (int j = 0; j < 4; ++j) {
      int n = bcol + wc * 64 + j * 16 + llo;
      int part = n >> 10, rem = n & 1023, hh = rem >> 6, dh = rem & 63;
      if (part == 2) {
        alignas(8) __hip_bfloat16 tv[4];
        #pragma unroll
        for (int r = 0; r < 4; ++r) tv[r] = __float2bfloat16(acc[i][j][r]);
        *reinterpret_cast<uint2*>(
            vT + (((size_t)(b * H_ + hh)) * DH_ + dh) * T_ + t) =
            *reinterpret_cast<const uint2*>(tv);
      } else {
        float sc = (part == 0) ? QSCALE : 1.0f;   // fold softmax scale into Q
        __hip_bfloat16* dst = (part == 0) ? q_ws : k_ws;
        #pragma unroll
        for (int r = 0; r < 4; ++r)
          dst[(((size_t)(b * H_ + hh)) * T_ + t + r) * DH_ + dh] =
              __float2bfloat16(acc[i][j][r] * sc);
      }
    }
  }
}

// GEMM2: out = y @ w_out (f32 output). 128x64 tile -> 512 blocks (2/CU).
__global__ __launch_bounds__(256) void k_gemm_out(
    const __hip_bfloat16* __restrict__ A, const __hip_bfloat16* __restrict__ BT,
    float* __restrict__ C) {
  alignas(16) __shared__ __hip_bfloat16 As[128 * 32];
  alignas(16) __shared__ __hip_bfloat16 Bs[64 * 32];
  f32x4 acc[4][2] = {};
  const int brow = blockIdx.y * 128, bcol = blockIdx.x * 64;
  gemm_core<128, 64, 4, 2>(A, BT, DM_, brow, bcol, As, Bs, acc);
  const int tid = threadIdx.x, wave = tid >> 6, lane = tid & 63;
  const int wr = wave >> 1, wc = wave & 1;
  const int llo = lane & 15, lhi = lane >> 4;
  #pragma unroll
  for (int i = 0; i < 4; ++i)
    #pragma unroll
    for (int j = 0; j < 2; ++j) {
      int n = bcol + wc * 32 + j * 16 + llo;
      #pragma unroll
      for (int r = 0; r < 4; ++r) {
        int m = brow + wr * 64 + i * 16 + lhi * 4 + r;
        C[(size_t)m * DM_ + n] = acc[i][j][r];
      }
    }
}

// ---------------- flash attention (causal), v9 ----------------
// QBLK=32 per wave (two 16-row fragments) -> each K/V fragment read feeds 2x
// MFMA; V fragments register-cached across both P half-phases; Ps roundtrip
// split into two 2KB per-wave phases. LDS bytes per q-row ~halved vs v8.
// Block = 256 thr (4 waves) = 2 groups of 2 waves. Group A (waves 0-1):
// q-tile qtA=31-p (64 rows); group B (waves 2-3): qtB=p, own tiles 0..p then
// help A with tiles 31-p..17 (tile = 32-j). A runs 17 iters (0..16), B 16.
// XCD remap kept (v8, 4.2x FETCH cut). v7-style single-syncthreads 2-slot
// ring per group. Combine: B -> LDS -> A before epilogue.
__global__ __launch_bounds__(256, 2) void k_attn(
    const __hip_bfloat16* __restrict__ Q, const __hip_bfloat16* __restrict__ Kk,
    const __hip_bfloat16* __restrict__ VT, __hip_bfloat16* __restrict__ Y) {
  alignas(16) __shared__ __hip_bfloat16 Ks[2][2][64 * 64];  // [group][slot]
  alignas(16) __shared__ __hip_bfloat16 Vs[2][2][64 * 64];  // [dh][t'] swizzled
  alignas(16) __shared__ __hip_bfloat16 Ps[4][16 * 64];
  // XCD-locality remap (dispatch round-robins XCDs by linear id)
  const int bid = blockIdx.x;                 // 0..511
  const int xcd = bid & 7, idx = bid >> 3;    // idx 0..63
  const int bh = ((idx & 3) << 3) | xcd;      // 4 bh per XCD
  const int p  = idx >> 2;                    // 0..15
  const int tid = threadIdx.x, wave = tid >> 6, lane = tid & 63;
  const int llo = lane & 15, lhi = lane >> 4;
  const int group = wave >> 1, wg = wave & 1;
  const int qtA = 31 - p, qtB = p;
  const int qt_own = group ? qtB : qtA;
  const int qr_own  = qt_own * 64 + wg * 32;  // wave's 32 own q-rows
  const int qr_help = qtA * 64 + wg * 32;     // B's help rows (A's q-tile)

  const __hip_bfloat16* kb = Kk + (size_t)bh * T_ * DH_;
  const __hip_bfloat16* vb = VT + (size_t)bh * DH_ * T_;

  const int srow = lane >> 3;                // 0..7
  const int schunk = (lane & 7) ^ srow;      // involution XOR (write-side)

  // tile sequence at iter j (-1 = idle)
  auto seq = [&](int j) -> int {
    if (group == 0) return (j <= 16) ? j : -1;        // A: tiles 0..16
    if (j <= p) return j;                             // B own: 0..p
    if (j <= 15) return 32 - j;                       // B help: 31-p .. 17
    return -1;
  };
  // wave stages 32 rows of K and 32 rows of V^T (8 gloads)
  auto stage = [&](int tile, int slt) {
    #pragma unroll
    for (int g = 0; g < 4; ++g) {
      const int rb = wg * 32 + g * 8;
      gload_lds16(kb + (size_t)(tile * 64 + rb + srow) * DH_ + schunk * 8,
                  &Ks[group][slt][rb * 64]);
      gload_lds16(vb + (size_t)(rb + srow) * T_ + tile * 64 + schunk * 8,
                  &Vs[group][slt][rb * 64]);
    }
  };

  bf16x8 aq_own[2][2], aq_help[2][2];
  #pragma unroll
  for (int f = 0; f < 2; ++f)
    #pragma unroll
    for (int k0 = 0; k0 < 2; ++k0) {
      aq_own[f][k0] = *reinterpret_cast<const bf16x8*>(
          Q + ((size_t)bh * T_ + qr_own + f * 16 + llo) * DH_ + k0 * 32 + lhi * 8);
      aq_help[f][k0] = *reinterpret_cast<const bf16x8*>(
          Q + ((size_t)bh * T_ + qr_help + f * 16 + llo) * DH_ + k0 * 32 + lhi * 8);
    }

  float l_own[2][4] = {}, l_help[2][4] = {};
  f32x4 o_own[2][4] = {}, o_help[2][4] = {};

  stage(0, 0);           // seq(0)=0 for both groups
  __syncthreads();

  for (int j = 0; j <= 16; ++j) {
    const int s1 = seq(j + 1);
    if (s1 >= 0) stage(s1, (j + 1) & 1);   // issue next stage before compute
    const int tc = seq(j);
    if (tc >= 0) {
      const __hip_bfloat16* ksb = &Ks[group][j & 1][0];
      const __hip_bfloat16* vsb = &Vs[group][j & 1][0];
      const bool own = (group == 0) || (j <= p);
      const bf16x8 (*aq)[2] = own ? aq_own : aq_help;
      f32x4 (*o)[4]  = own ? o_own : o_help;
      float (*lr)[4] = own ? l_own : l_help;
      const int qb = own ? qr_own : qr_help;
      const int qt = own ? qt_own : qtA;

      // ---- QK^T: 8 K-frag reads feed 16 MFMA (2 q-frags) ----
      f32x4 s[2][4];
      __builtin_amdgcn_s_setprio(1);
      #pragma unroll
      for (int jn = 0; jn < 4; ++jn) {
        const __hip_bfloat16* krow = ksb + (jn * 16 + llo) * 64;
        bf16x8 b0 = *reinterpret_cast<const bf16x8*>(krow + ((lhi ^ (llo & 7)) << 3));
        bf16x8 b1 = *reinterpret_cast<const bf16x8*>(krow + (((4 + lhi) ^ (llo & 7)) << 3));
        #pragma unroll
        for (int f = 0; f < 2; ++f) {
          f32x4 z = {};
          z = __builtin_amdgcn_mfma_f32_16x16x32_bf16(aq[f][0], b0, z, 0, 0, 0);
          z = __builtin_amdgcn_mfma_f32_16x16x32_bf16(aq[f][1], b1, z, 0, 0, 0);
          s[f][jn] = z;
        }
      }
      __builtin_amdgcn_s_setprio(0);
      // causal mask only on the accumulator's diagonal tile
      if (tc == qt) {
        #pragma unroll
        for (int f = 0; f < 2; ++f)
          #pragma unroll
          for (int jn = 0; jn < 4; ++jn)
            #pragma unroll
            for (int r = 0; r < 4; ++r) {
              int qrow = qb + f * 16 + lhi * 4 + r;
              int tcol = tc * 64 + jn * 16 + llo;
              if (tcol > qrow) s[f][jn][r] = -INFINITY;
            }
      }
      // static-max softmax: p = exp2(s - FIXED_M), in place
      #pragma unroll
      for (int f = 0; f < 2; ++f)
        #pragma unroll
        for (int jn = 0; jn < 4; ++jn)
          #pragma unroll
          for (int r = 0; r < 4; ++r) {
            float pv = __builtin_amdgcn_exp2f(s[f][jn][r] - FIXED_M);
            s[f][jn][r] = pv;
            lr[f][r] += pv;
          }
      // ---- V fragments once into registers (reused by both P phases) ----
      bf16x8 vb0[4], vb1[4];
      #pragma unroll
      for (int jd = 0; jd < 4; ++jd) {
        const __hip_bfloat16* vrow = vsb + (jd * 16 + llo) * 64;
        vb0[jd] = *reinterpret_cast<const bf16x8*>(vrow + ((lhi ^ (llo & 7)) << 3));
        vb1[jd] = *reinterpret_cast<const bf16x8*>(vrow + (((4 + lhi) ^ (llo & 7)) << 3));
      }
      // ---- PV in two half-phases through per-wave Ps (2KB) ----
      #pragma unroll
      for (int f = 0; f < 2; ++f) {
        #pragma unroll
        for (int jn = 0; jn < 4; ++jn)
          #pragma unroll
          for (int r = 0; r < 4; ++r) {
            int row = lhi * 4 + r, col = jn * 16 + llo;
            Ps[wave][row * 64 + (col ^ ((row & 7) << 3))] = __float2bfloat16(s[f][jn][r]);
          }
        bf16x8 ap0 = *reinterpret_cast<const bf16x8*>(
            &Ps[wave][llo * 64 + ((lhi ^ (llo & 7)) << 3)]);
        bf16x8 ap1 = *reinterpret_cast<const bf16x8*>(
            &Ps[wave][llo * 64 + (((4 + lhi) ^ (llo & 7)) << 3)]);
        __builtin_amdgcn_s_setprio(1);
        #pragma unroll
        for (int jd = 0; jd < 4; ++jd) {
          o[f][jd] = __builtin_amdgcn_mfma_f32_16x16x32_bf16(ap0, vb0[jd], o[f][jd], 0, 0, 0);
          o[f][jd] = __builtin_amdgcn_mfma_f32_16x16x32_bf16(ap1, vb1[jd], o[f][jd], 0, 0, 0);
        }
        __builtin_amdgcn_s_setprio(0);
      }
    }
    __syncthreads();   // drains stage (vmcnt0) + guards 2-slot ring reuse
  }

  // ---- combine: B's help accumulator -> A (LDS, reusing group-0 K slots) ----
  float* Oh = reinterpret_cast<float*>(&Ks[0][0][0]);   // 16 KB
  float* Lh = reinterpret_cast<float*>(&Vs[0][0][0]);   // 64 f32
  if (group == 1) {
    #pragma unroll
    for (int f = 0; f < 2; ++f)
      #pragma unroll
      for (int r = 0; r < 4; ++r) {
        float lh = l_help[f][r];
        #pragma unroll
        for (int d = 1; d < 16; d <<= 1) lh += __shfl_xor(lh, d);
        if (llo == 0) Lh[wg * 32 + f * 16 + lhi * 4 + r] = lh;
      }
    #pragma unroll
    for (int f = 0; f < 2; ++f)
      #pragma unroll
      for (int jd = 0; jd < 4; ++jd)
        #pragma unroll
        for (int r = 0; r < 4; ++r)
          Oh[(wg * 32 + f * 16 + lhi * 4 + r) * 64 + jd * 16 + llo] = o_help[f][jd][r];
  }
  __syncthreads();

  float lfin[2][4];
  #pragma unroll
  for (int f = 0; f < 2; ++f)
    #pragma unroll
    for (int r = 0; r < 4; ++r) {
      float ps = l_own[f][r];
      #pragma unroll
      for (int d = 1; d < 16; d <<= 1) ps += __shfl_xor(ps, d);
      lfin[f][r] = ps;
    }
  if (group == 0) {
    #pragma unroll
    for (int f = 0; f < 2; ++f)
      #pragma unroll
      for (int r = 0; r < 4; ++r)
        lfin[f][r] += Lh[wg * 32 + f * 16 + lhi * 4 + r];
    #pragma unroll
    for (int f = 0; f < 2; ++f)
      #pragma unroll
      for (int jd = 0; jd < 4; ++jd)
        #pragma unroll
        for (int r = 0; r < 4; ++r)
          o_own[f][jd][r] += Oh[(wg * 32 + f * 16 + lhi * 4 + r) * 64 + jd * 16 + llo];
  }

  // epilogue: y[b][t][h*64+dh] for own q-rows
  const int b = bh >> 4, h = bh & 15;
  #pragma unroll
  for (int f = 0; f < 2; ++f)
    #pragma unroll
    for (int jd = 0; jd < 4; ++jd)
      #pragma unroll
      for (int r = 0; r < 4; ++r) {
        int trow = qr_own + f * 16 + lhi * 4 + r;
        int col = h * 64 + jd * 16 + llo;
        Y[((size_t)(b * T_ + trow)) * DM_ + col] =
            __float2bfloat16(o_own[f][jd][r] / lfin[f][r]);
      }
}

// ---------------- launch ----------------
extern "C" void kernel_launch(void* const* d_in, const int* in_sizes, int n_in,
                              void* d_out, int out_size, void* d_ws, size_t ws_size,
                              hipStream_t stream) {
  const float* x     = (const float*)d_in[0];
  const float* w_qkv = (const float*)d_in[1];
  const float* w_out = (const float*)d_in[2];
  float* out = (float*)d_out;
  char* ws = (char*)d_ws;

  size_t off = 0;
  __hip_bfloat16* xb    = (__hip_bfloat16*)(ws + off); off += (size_t)M_ * DM_ * 2;      // 8 MiB
  __hip_bfloat16* wqkvT = (__hip_bfloat16*)(ws + off); off += (size_t)3 * DM_ * DM_ * 2; // 6 MiB
  __hip_bfloat16* woutT = (__hip_bfloat16*)(ws + off); off += (size_t)DM_ * DM_ * 2;     // 2 MiB
  __hip_bfloat16* q_ws  = (__hip_bfloat16*)(ws + off); off += (size_t)M_ * DM_ * 2;      // 8 MiB
  __hip_bfloat16* k_ws  = (__hip_bfloat16*)(ws + off); off += (size_t)M_ * DM_ * 2;      // 8 MiB
  __hip_bfloat16* vT    = (__hip_bfloat16*)(ws + off); off += (size_t)M_ * DM_ * 2;      // 8 MiB
  __hip_bfloat16* y_ws  = (__hip_bfloat16*)(ws + off); off += (size_t)M_ * DM_ * 2;      // 8 MiB
  (void)ws_size; (void)in_sizes; (void)n_in; (void)out_size;

  // convert inputs to bf16 (weights pre-transposed to B^T layout)
  k_cvt_bf16<<<(M_ * DM_ / 4 + 255) / 256, 256, 0, stream>>>(x, xb, M_ * DM_ / 4);
  k_cvtT<<<dim3(3 * DM_ / 32, DM_ / 32), 256, 0, stream>>>(w_qkv, wqkvT, DM_, 3 * DM_);
  k_cvtT<<<dim3(DM_ / 32, DM_ / 32), 256, 0, stream>>>(w_out, woutT, DM_, DM_);

  // qkv projection (Q pre-scaled; V written directly transposed)
  k_gemm_qkv<<<dim3(3 * DM_ / 128, M_ / 128), 256, 0, stream>>>(xb, wqkvT, q_ws, k_ws, vT);

  // causal flash attention (32q/wave, balanced help, XCD remap)
  k_attn<<<dim3(512), 256, 0, stream>>>(q_ws, k_ws, vT, y_ws);

  // output projection (f32 out), 128x64 tiles -> 512 blocks
  k_gemm_out<<<dim3(DM_ / 64, M_ / 128), 256, 0, stream>>>(y_ws, woutT, out);
}

// Round 10
// 106.088 us; speedup vs baseline: 1.1277x; 1.1277x over previous
//
#include <hip/hip_runtime.h>
#include <hip/hip_bf16.h>
#include <stdint.h>

typedef __bf16 bf16x8 __attribute__((ext_vector_type(8)));
typedef float  f32x4  __attribute__((ext_vector_type(4)));

#define B_   2
#define T_   2048
#define H_   16
#define DH_  64
#define DM_  1024
#define BH_  (B_*H_)   // 32
#define M_   (B_*T_)   // 4096

#define QSCALE 0.18033688f   // 1/sqrt(64) * log2(e), folded into Q
#define FIXED_M 8.0f         // static softmax max (exp2 domain)

// ---- async global->LDS, 16B per lane; LDS dest must be wave-uniform base ----
static __device__ __forceinline__ void gload_lds16(const void* g, void* lds) {
  __builtin_amdgcn_global_load_lds(
      (const __attribute__((address_space(1))) void*)(uintptr_t)g,
      (__attribute__((address_space(3))) void*)(uint32_t)(uintptr_t)lds,
      16, 0, 0);
}

// ---------------- conversion kernels ----------------
__global__ void k_cvt_bf16(const float* __restrict__ in, __hip_bfloat16* __restrict__ out, int n4) {
  int i = blockIdx.x * blockDim.x + threadIdx.x;
  if (i < n4) {
    float4 v = reinterpret_cast<const float4*>(in)[i];
    alignas(8) __hip_bfloat16 t[4] = {__float2bfloat16(v.x), __float2bfloat16(v.y),
                                      __float2bfloat16(v.z), __float2bfloat16(v.w)};
    reinterpret_cast<uint2*>(out)[i] = *reinterpret_cast<const uint2*>(t);
  }
}

// in [K][N] f32 row-major -> out [N][K] bf16 row-major (B^T for gemm_bt)
__global__ void k_cvtT(const float* __restrict__ in, __hip_bfloat16* __restrict__ out, int K, int N) {
  __shared__ float tile[32][33];
  int n0 = blockIdx.x * 32, k0 = blockIdx.y * 32;
  int tid = threadIdx.x;
  int kl = tid >> 3, n4 = (tid & 7) * 4;
  float4 v = *reinterpret_cast<const float4*>(in + (size_t)(k0 + kl) * N + n0 + n4);
  tile[kl][n4 + 0] = v.x; tile[kl][n4 + 1] = v.y; tile[kl][n4 + 2] = v.z; tile[kl][n4 + 3] = v.w;
  __syncthreads();
  int nl = tid >> 3, k4 = (tid & 7) * 4;
  alignas(8) __hip_bfloat16 t[4];
  #pragma unroll
  for (int j = 0; j < 4; ++j) t[j] = __float2bfloat16(tile[k4 + j][nl]);
  *reinterpret_cast<uint2*>(out + (size_t)(n0 + nl) * K + k0 + k4) = *reinterpret_cast<const uint2*>(t);
}

// ---- pipelined bf16 GEMM core (B^T input), BK=32, 4 waves, 3-slot ring ----
// Per K-step: vmcnt(LOADS) confirms own stage(ks); s_barrier publishes;
// stage(ks+2) into slot (ks+2)%3 (last read at compute(ks-1), done before
// barrier); ds_read slot ks%3 + MFMA. ONE barrier per step, no vmcnt(0)
// drain in the loop (v6-attn's proven counted-vmcnt pattern).
template<int BM, int BN, int FM, int FN>
static __device__ __forceinline__ void gemm_core_pipe(
    const __hip_bfloat16* __restrict__ A, const __hip_bfloat16* __restrict__ BT,
    int K, int brow, int bcol, __hip_bfloat16* As, __hip_bfloat16* Bs,
    f32x4 acc[FM][FN]) {
  constexpr int WGN = BN / (16 * FN);
  constexpr int LOADS = BM / 64 + BN / 64;       // gloads per wave per stage
  constexpr int ASLOT = BM * 32, BSLOT = BN * 32;
  const int tid = threadIdx.x, wave = tid >> 6, lane = tid & 63;
  const int wr = wave / WGN, wc = wave % WGN;
  const int llo = lane & 15, lhi = lane >> 4;
  const int nk = K / 32;
  auto stage = [&](int ks, int slot) {
    #pragma unroll
    for (int c = wave; c < BM / 16; c += 4)
      gload_lds16(A + (size_t)(brow + c * 16 + (lane >> 2)) * K + ks * 32 + (lane & 3) * 8,
                  As + slot * ASLOT + c * 512);
    #pragma unroll
    for (int c = wave; c < BN / 16; c += 4)
      gload_lds16(BT + (size_t)(bcol + c * 16 + (lane >> 2)) * K + ks * 32 + (lane & 3) * 8,
                  Bs + slot * BSLOT + c * 512);
  };
  stage(0, 0);
  stage(1, 1);
  for (int ks = 0; ks < nk; ++ks) {
    if constexpr (LOADS == 4)      asm volatile("s_waitcnt vmcnt(4)" ::: "memory");
    else if constexpr (LOADS == 3) asm volatile("s_waitcnt vmcnt(3)" ::: "memory");
    else                           asm volatile("s_waitcnt vmcnt(0)" ::: "memory");
    __builtin_amdgcn_sched_barrier(0);
    __builtin_amdgcn_s_barrier();
    __builtin_amdgcn_sched_barrier(0);
    const int s2 = (ks + 2 < nk) ? ks + 2 : nk - 1;  // clamped redundant tail
    stage(s2, (ks + 2) % 3);
    const __hip_bfloat16* Asl = As + (ks % 3) * ASLOT;
    const __hip_bfloat16* Bsl = Bs + (ks % 3) * BSLOT;
    bf16x8 a[FM], b[FN];
    #pragma unroll
    for (int i = 0; i < FM; ++i)
      a[i] = *reinterpret_cast<const bf16x8*>(Asl + (wr * FM * 16 + i * 16 + llo) * 32 + lhi * 8);
    #pragma unroll
    for (int j = 0; j < FN; ++j)
      b[j] = *reinterpret_cast<const bf16x8*>(Bsl + (wc * FN * 16 + j * 16 + llo) * 32 + lhi * 8);
    __builtin_amdgcn_s_setprio(1);
    #pragma unroll
    for (int i = 0; i < FM; ++i)
      #pragma unroll
      for (int j = 0; j < FN; ++j)
        acc[i][j] = __builtin_amdgcn_mfma_f32_16x16x32_bf16(a[i], b[j], acc[i][j], 0, 0, 0);
    __builtin_amdgcn_s_setprio(0);
  }
  asm volatile("s_waitcnt vmcnt(0)" ::: "memory");
}

// GEMM1: qkv = xb @ w_qkv ; Q (pre-scaled) / K as [bh][t][dh]; V directly
// transposed to [bh][dh][t] (4 consecutive t per lane -> packed 8B store).
__global__ __launch_bounds__(256) void k_gemm_qkv(
    const __hip_bfloat16* __restrict__ A, const __hip_bfloat16* __restrict__ BT,
    __hip_bfloat16* __restrict__ q_ws, __hip_bfloat16* __restrict__ k_ws,
    __hip_bfloat16* __restrict__ vT) {
  alignas(16) __shared__ __hip_bfloat16 As[3 * 128 * 32];
  alignas(16) __shared__ __hip_bfloat16 Bs[3 * 128 * 32];
  f32x4 acc[4][4] = {};
  const int brow = blockIdx.y * 128, bcol = blockIdx.x * 128;
  gemm_core_pipe<128, 128, 4, 4>(A, BT, DM_, brow, bcol, As, Bs, acc);
  const int tid = threadIdx.x, wave = tid >> 6, lane = tid & 63;
  const int wr = wave >> 1, wc = wave & 1;
  const int llo = lane & 15, lhi = lane >> 4;
  #pragma unroll
  for (int i = 0; i < 4; ++i) {
    const int tbase = brow + wr * 64 + i * 16 + lhi * 4;  // 4 consecutive t
    const int b = tbase >> 11, t = tbase & 2047;
    #pragma unroll
    for (int j = 0; j < 4; ++j) {
      int n = bcol + wc * 64 + j * 16 + llo;
      int part = n >> 10, rem = n & 1023, hh = rem >> 6, dh = rem & 63;
      if (part == 2) {
        alignas(8) __hip_bfloat16 tv[4];
        #pragma unroll
        for (int r = 0; r < 4; ++r) tv[r] = __float2bfloat16(acc[i][j][r]);
        *reinterpret_cast<uint2*>(
            vT + (((size_t)(b * H_ + hh)) * DH_ + dh) * T_ + t) =
            *reinterpret_cast<const uint2*>(tv);
      } else {
        float sc = (part == 0) ? QSCALE : 1.0f;   // fold softmax scale into Q
        __hip_bfloat16* dst = (part == 0) ? q_ws : k_ws;
        #pragma unroll
        for (int r = 0; r < 4; ++r)
          dst[(((size_t)(b * H_ + hh)) * T_ + t + r) * DH_ + dh] =
              __float2bfloat16(acc[i][j][r] * sc);
      }
    }
  }
}

// GEMM2: out = y @ w_out (f32 output). 128x64 tile -> 512 blocks (2/CU).
__global__ __launch_bounds__(256) void k_gemm_out(
    const __hip_bfloat16* __restrict__ A, const __hip_bfloat16* __restrict__ BT,
    float* __restrict__ C) {
  alignas(16) __shared__ __hip_bfloat16 As[3 * 128 * 32];
  alignas(16) __shared__ __hip_bfloat16 Bs[3 * 64 * 32];
  f32x4 acc[4][2] = {};
  const int brow = blockIdx.y * 128, bcol = blockIdx.x * 64;
  gemm_core_pipe<128, 64, 4, 2>(A, BT, DM_, brow, bcol, As, Bs, acc);
  const int tid = threadIdx.x, wave = tid >> 6, lane = tid & 63;
  const int wr = wave >> 1, wc = wave & 1;
  const int llo = lane & 15, lhi = lane >> 4;
  #pragma unroll
  for (int i = 0; i < 4; ++i)
    #pragma unroll
    for (int j = 0; j < 2; ++j) {
      int n = bcol + wc * 32 + j * 16 + llo;
      #pragma unroll
      for (int r = 0; r < 4; ++r) {
        int m = brow + wr * 64 + i * 16 + lhi * 4 + r;
        C[(size_t)m * DM_ + n] = acc[i][j][r];
      }
    }
}

// ---------------- flash attention (causal), v6 (best measured: 41.0 us) ----
// Pair-balanced 8-wave blocks; 4-buffer K/V ring, stage-ahead-2, counted
// s_waitcnt vmcnt(4) + raw s_barrier; static-max softmax; XOR-swizzled K/V.
__global__ __launch_bounds__(512) void k_attn(
    const __hip_bfloat16* __restrict__ Q, const __hip_bfloat16* __restrict__ Kk,
    const __hip_bfloat16* __restrict__ VT, __hip_bfloat16* __restrict__ Y) {
  alignas(16) __shared__ __hip_bfloat16 Ks[4][64 * 64];
  alignas(16) __shared__ __hip_bfloat16 Vs[4][64 * 64];   // [dh][t'] swizzled
  alignas(16) __shared__ __hip_bfloat16 Ps[8][16 * 64];
  const int bh = blockIdx.y;
  const int p  = blockIdx.x;                 // 0..15
  const int tid = threadIdx.x, wave = tid >> 6, lane = tid & 63;
  const int llo = lane & 15, lhi = lane >> 4;
  const int qt   = (wave < 4) ? (31 - p) : p;
  const int myNt = qt + 1;
  const int ntA  = 32 - p;                   // block loop length (>= 17)
  const int q0 = qt * 64;
  const int qbase = q0 + (wave & 3) * 16;

  const __hip_bfloat16* kb = Kk + (size_t)bh * T_ * DH_;
  const __hip_bfloat16* vb = VT + (size_t)bh * DH_ * T_;

  const int srow = lane >> 3;                // 0..7
  const int schunk = (lane & 7) ^ srow;      // involution XOR
  const int rb = wave * 8;

  bf16x8 aq[2];
  #pragma unroll
  for (int k0 = 0; k0 < 2; ++k0)
    aq[k0] = *reinterpret_cast<const bf16x8*>(
        Q + ((size_t)bh * T_ + qbase + llo) * DH_ + k0 * 32 + lhi * 8);

  float lrow[4] = {0.f, 0.f, 0.f, 0.f};      // lane-local partial row sums
  f32x4 o[4] = {};

  // prologue: stage tiles 0,1 into buffers 0,1 (ntA >= 17 so both exist)
  gload_lds16(kb + (size_t)(rb + srow) * DH_ + schunk * 8, &Ks[0][rb * 64]);
  gload_lds16(vb + (size_t)(rb + srow) * T_ + schunk * 8, &Vs[0][rb * 64]);
  gload_lds16(kb + (size_t)(64 + rb + srow) * DH_ + schunk * 8, &Ks[1][rb * 64]);
  gload_lds16(vb + (size_t)(rb + srow) * T_ + 64 + schunk * 8, &Vs[1][rb * 64]);

  for (int it = 0; it < ntA; ++it) {
    const int cur = it & 3;
    // stage tile it+2 (clamped at tail -> redundant stage into a dead buffer;
    // keeps 2 loads/wave/iter so vmcnt(4) is exact in all iterations)
    {
      const int ts = (it + 2 < ntA) ? (it + 2) : (ntA - 1);
      const int bs = (it + 2) & 3;
      const int tn = ts * 64;
      gload_lds16(kb + (size_t)(tn + rb + srow) * DH_ + schunk * 8, &Ks[bs][rb * 64]);
      gload_lds16(vb + (size_t)(rb + srow) * T_ + tn + schunk * 8, &Vs[bs][rb * 64]);
    }
    // wait own tile-it stage (4 newer loads stay in flight), then sync waves
    asm volatile("s_waitcnt vmcnt(4)" ::: "memory");
    __builtin_amdgcn_sched_barrier(0);
    __builtin_amdgcn_s_barrier();
    __builtin_amdgcn_sched_barrier(0);

    if (it < myNt) {    // wave-uniform guard (waves 4-7 finish early)
      const __hip_bfloat16* ksb = Ks[cur];
      const __hip_bfloat16* vsb = Vs[cur];

      // S = Q K^T (K fragments from swizzled LDS; Q pre-scaled)
      f32x4 s[4];
      __builtin_amdgcn_s_setprio(1);
      #pragma unroll
      for (int jn = 0; jn < 4; ++jn) {
        const __hip_bfloat16* krow = ksb + (jn * 16 + llo) * 64;
        bf16x8 b0 = *reinterpret_cast<const bf16x8*>(krow + ((lhi ^ (llo & 7)) << 3));
        bf16x8 b1 = *reinterpret_cast<const bf16x8*>(krow + (((4 + lhi) ^ (llo & 7)) << 3));
        f32x4 z = {};
        z = __builtin_amdgcn_mfma_f32_16x16x32_bf16(aq[0], b0, z, 0, 0, 0);
        z = __builtin_amdgcn_mfma_f32_16x16x32_bf16(aq[1], b1, z, 0, 0, 0);
        s[jn] = z;
      }
      __builtin_amdgcn_s_setprio(0);
      // causal mask only on the diagonal tile
      if (it == myNt - 1) {
        #pragma unroll
        for (int jn = 0; jn < 4; ++jn)
          #pragma unroll
          for (int r = 0; r < 4; ++r) {
            int qrow = qbase + lhi * 4 + r;
            int tcol = q0 + jn * 16 + llo;
            if (tcol > qrow) s[jn][r] = -INFINITY;
          }
      }
      // static-max softmax: p = exp2(s - FIXED_M); partial row-sum per lane
      #pragma unroll
      for (int jn = 0; jn < 4; ++jn)
        #pragma unroll
        for (int r = 0; r < 4; ++r) {
          float pv = __builtin_amdgcn_exp2f(s[jn][r] - FIXED_M);
          lrow[r] += pv;
          int row = lhi * 4 + r, col = jn * 16 + llo;
          Ps[wave][row * 64 + (col ^ ((row & 7) << 3))] = __float2bfloat16(pv);
        }
      // PV: A = P (swizzled per-wave LDS), B = V^T rows (swizzled LDS)
      bf16x8 ap0 = *reinterpret_cast<const bf16x8*>(
          &Ps[wave][llo * 64 + ((lhi ^ (llo & 7)) << 3)]);
      bf16x8 ap1 = *reinterpret_cast<const bf16x8*>(
          &Ps[wave][llo * 64 + (((4 + lhi) ^ (llo & 7)) << 3)]);
      __builtin_amdgcn_s_setprio(1);
      #pragma unroll
      for (int jd = 0; jd < 4; ++jd) {
        const __hip_bfloat16* vrow = vsb + (jd * 16 + llo) * 64;
        bf16x8 b0 = *reinterpret_cast<const bf16x8*>(vrow + ((lhi ^ (llo & 7)) << 3));
        bf16x8 b1 = *reinterpret_cast<const bf16x8*>(vrow + (((4 + lhi) ^ (llo & 7)) << 3));
        o[jd] = __builtin_amdgcn_mfma_f32_16x16x32_bf16(ap0, b0, o[jd], 0, 0, 0);
        o[jd] = __builtin_amdgcn_mfma_f32_16x16x32_bf16(ap1, b1, o[jd], 0, 0, 0);
      }
      __builtin_amdgcn_s_setprio(0);
    }
  }

  // final row-sum reduce (once) across the 16-lane group, then normalize
  float lr[4];
  #pragma unroll
  for (int r = 0; r < 4; ++r) {
    float ps = lrow[r];
    #pragma unroll
    for (int d = 1; d < 16; d <<= 1) ps += __shfl_xor(ps, d);
    lr[r] = ps;
  }
  // epilogue: y[b][t][h*64+dh]
  const int b = bh >> 4, h = bh & 15;
  #pragma unroll
  for (int jd = 0; jd < 4; ++jd)
    #pragma unroll
    for (int r = 0; r < 4; ++r) {
      int trow = qbase + lhi * 4 + r;
      int col = h * 64 + jd * 16 + llo;
      Y[((size_t)(b * T_ + trow)) * DM_ + col] = __float2bfloat16(o[jd][r] / lr[r]);
    }
}

// ---------------- launch ----------------
extern "C" void kernel_launch(void* const* d_in, const int* in_sizes, int n_in,
                              void* d_out, int out_size, void* d_ws, size_t ws_size,
                              hipStream_t stream) {
  const float* x     = (const float*)d_in[0];
  const float* w_qkv = (const float*)d_in[1];
  const float* w_out = (const float*)d_in[2];
  float* out = (float*)d_out;
  char* ws = (char*)d_ws;

  size_t off = 0;
  __hip_bfloat16* xb    = (__hip_bfloat16*)(ws + off); off += (size_t)M_ * DM_ * 2;      // 8 MiB
  __hip_bfloat16* wqkvT = (__hip_bfloat16*)(ws + off); off += (size_t)3 * DM_ * DM_ * 2; // 6 MiB
  __hip_bfloat16* woutT = (__hip_bfloat16*)(ws + off); off += (size_t)DM_ * DM_ * 2;     // 2 MiB
  __hip_bfloat16* q_ws  = (__hip_bfloat16*)(ws + off); off += (size_t)M_ * DM_ * 2;      // 8 MiB
  __hip_bfloat16* k_ws  = (__hip_bfloat16*)(ws + off); off += (size_t)M_ * DM_ * 2;      // 8 MiB
  __hip_bfloat16* vT    = (__hip_bfloat16*)(ws + off); off += (size_t)M_ * DM_ * 2;      // 8 MiB
  __hip_bfloat16* y_ws  = (__hip_bfloat16*)(ws + off); off += (size_t)M_ * DM_ * 2;      // 8 MiB
  (void)ws_size; (void)in_sizes; (void)n_in; (void)out_size;

  // convert inputs to bf16 (weights pre-transposed to B^T layout)
  k_cvt_bf16<<<(M_ * DM_ / 4 + 255) / 256, 256, 0, stream>>>(x, xb, M_ * DM_ / 4);
  k_cvtT<<<dim3(3 * DM_ / 32, DM_ / 32), 256, 0, stream>>>(w_qkv, wqkvT, DM_, 3 * DM_);
  k_cvtT<<<dim3(DM_ / 32, DM_ / 32), 256, 0, stream>>>(w_out, woutT, DM_, DM_);

  // qkv projection (Q pre-scaled; V written directly transposed)
  k_gemm_qkv<<<dim3(3 * DM_ / 128, M_ / 128), 256, 0, stream>>>(xb, wqkvT, q_ws, k_ws, vT);

  // causal flash attention (v6: pair-balanced, counted-vmcnt 4-buffer ring)
  k_attn<<<dim3(T_ / 128, BH_), 512, 0, stream>>>(q_ws, k_ws, vT, y_ws);

  // output projection (f32 out), 128x64 tiles -> 512 blocks
  k_gemm_out<<<dim3(DM_ / 64, M_ / 128), 256, 0, stream>>>(y_ws, woutT, out);
}